// Round 1
// baseline (1255.660 us; speedup 1.0000x reference)
//
#include <hip/hip_runtime.h>
#include <cstdint>
#include <cstddef>

#define BSZ 16
#define TLEN 2048
#define CDIM 1024
#define DUDIM 1024
#define OUTDIM 512
#define MAXF 512

// ============================================================================
// Kernel 1: g[row] = sum_du Wp[du] * relu( enc[row,:] . Wd[du,:] + bd[du] )
// 128x128 tile, BK=32, 256 threads, 8x8 micro-tile. Grid (256 row-tiles, 8 du-tiles).
// Partial du-sums combined via atomicAdd into g[32768] (g pre-zeroed).
// ============================================================================
__global__ __launch_bounds__(256) void k1_weight_gemm(
    const float* __restrict__ enc, const float* __restrict__ Wd,
    const float* __restrict__ bd, const float* __restrict__ Wp,
    float* __restrict__ g)
{
    __shared__ float As[32][128];
    __shared__ float Bs[32][128];
    __shared__ float red[16][128];

    const int tid = threadIdx.x;
    const int tx = tid & 15;        // m-group
    const int ty = tid >> 4;        // n-group
    const int lr = tid & 127;       // staging row
    const int lh = tid >> 7;        // staging k-half
    const long row0 = (long)blockIdx.x * 128;
    const int du0 = blockIdx.y * 128;

    float acc[8][8];
#pragma unroll
    for (int i = 0; i < 8; i++)
#pragma unroll
        for (int j = 0; j < 8; j++) acc[i][j] = 0.f;

    const float* abase = enc + (row0 + lr) * (long)CDIM + lh * 16;
    const float* bbase = Wd + (long)(du0 + lr) * CDIM + lh * 16;

    for (int k0 = 0; k0 < CDIM; k0 += 32) {
        float av[16], bv[16];
#pragma unroll
        for (int j = 0; j < 4; j++) {
            *(float4*)&av[j * 4] = *(const float4*)(abase + k0 + j * 4);
            *(float4*)&bv[j * 4] = *(const float4*)(bbase + k0 + j * 4);
        }
        __syncthreads();
#pragma unroll
        for (int j = 0; j < 16; j++) {
            As[lh * 16 + j][lr] = av[j];
            Bs[lh * 16 + j][lr] = bv[j];
        }
        __syncthreads();
#pragma unroll 8
        for (int kk = 0; kk < 32; kk++) {
            float a[8], b[8];
            *(float4*)&a[0] = *(const float4*)&As[kk][tx * 4];
            *(float4*)&a[4] = *(const float4*)&As[kk][tx * 4 + 64];
            *(float4*)&b[0] = *(const float4*)&Bs[kk][ty * 4];
            *(float4*)&b[4] = *(const float4*)&Bs[kk][ty * 4 + 64];
#pragma unroll
            for (int i = 0; i < 8; i++)
#pragma unroll
                for (int j = 0; j < 8; j++)
                    acc[i][j] += a[i] * b[j];
        }
    }

    // epilogue: relu(acc + bd) * Wp, reduce over this block's 128 du
    float pm[8];
    {
        float bdv[8], wpv[8];
#pragma unroll
        for (int j = 0; j < 8; j++) {
            int n = du0 + ty * 4 + (j & 3) + (j >> 2) * 64;
            bdv[j] = bd[n];
            wpv[j] = Wp[n];
        }
#pragma unroll
        for (int i = 0; i < 8; i++) {
            float s = 0.f;
#pragma unroll
            for (int j = 0; j < 8; j++) {
                float h = acc[i][j] + bdv[j];
                h = h > 0.f ? h : 0.f;
                s += wpv[j] * h;
            }
            pm[i] = s;
        }
    }
    __syncthreads();  // done with As/Bs; red is separate but sync ordering anyway
#pragma unroll
    for (int i = 0; i < 8; i++) {
        int m = tx * 4 + (i & 3) + (i >> 2) * 64;
        red[ty][m] = pm[i];
    }
    __syncthreads();
    if (tid < 128) {
        float s = 0.f;
#pragma unroll
        for (int y = 0; y < 16; y++) s += red[y][tid];
        atomicAdd(&g[row0 + tid], s);
    }
}

// ============================================================================
// Kernel 2: per-batch sigmoid + masked sum + scale + sequential CIF scan.
// One block per batch. Emits: quantity_out, per-t coefficients (c_a, c_b),
// fire times, n_fired, and the mask/durations outputs.
// Scan replicates reference fp32 op order exactly.
// ============================================================================
__global__ __launch_bounds__(256) void k2_scan(
    const float* __restrict__ g, const int* __restrict__ in_len,
    const int* __restrict__ tgt_len, const float* __restrict__ bp,
    float* __restrict__ c_a, float* __restrict__ c_b,
    int* __restrict__ fire_t, int* __restrict__ n_fired,
    float* __restrict__ out_mask, float* __restrict__ out_dur,
    float* __restrict__ out_qty)
{
    __shared__ float w[TLEN];
    __shared__ int fires[MAXF];
    __shared__ float ssum[256];
    __shared__ float s_scale;
    __shared__ int s_nf;

    const int b = blockIdx.x;
    const int tid = threadIdx.x;
    const int len = in_len[b];
    const float bpv = bp[0];

    float local = 0.f;
    for (int t = tid; t < TLEN; t += 256) {
        float gv = g[b * TLEN + t] + bpv;
        float s = 1.f / (1.f + expf(-gv));
        float ow = (t < len) ? s : 0.f;
        w[t] = ow;
        local += ow;
    }
    ssum[tid] = local;
    __syncthreads();
    for (int st = 128; st > 0; st >>= 1) {
        if (tid < st) ssum[tid] += ssum[tid + st];
        __syncthreads();
    }
    if (tid == 0) {
        float org_sum = ssum[0];
        out_qty[b] = org_sum;
        s_scale = (float)tgt_len[b] / (org_sum + 1e-8f);
    }
    __syncthreads();
    float scale = s_scale;
    for (int t = tid; t < TLEN; t += 256) w[t] *= scale;
    __syncthreads();

    if (tid == 0) {
        float accw = 0.f;
        int k = 0;
        for (int t = 0; t < len; t++) {   // w==0 beyond len -> state frozen
            float wt = w[t];
            float aw = accw + wt;
            if (aw >= 1.0f) {
                float remained = 1.f - accw;      // exact reference order
                c_a[b * TLEN + t] = remained;
                c_b[b * TLEN + t] = wt - remained;
                if (k < MAXF) fires[k] = t;
                k++;
                accw = wt - remained;
            } else {
                c_a[b * TLEN + t] = wt;
                c_b[b * TLEN + t] = 0.f;
                accw = aw;
            }
        }
        s_nf = (k < MAXF) ? k : MAXF;
        n_fired[b] = s_nf;
    }
    __syncthreads();

    const int nf = s_nf;
    for (int j = tid; j < nf; j += 256) {
        int tj = fires[j];
        fire_t[b * MAXF + j] = tj;
        out_mask[b * TLEN + j] = 1.0f;
        int prev = (j == 0) ? 0 : fires[j - 1];
        out_dur[b * TLEN + j] = (float)(tj - prev);
    }
    if (tid == 0 && nf == 0) out_mask[b * TLEN] = 1.0f;  // reference fallback
}

// ============================================================================
// Kernel 3a: compact fired frames. One block per (frame k, batch b).
// frame k = c_b[t_prev]*e[t_prev] + sum_{t in (t_prev, t_k]} c_a[t]*e[t]
// accumulated in ascending t — same order as the reference scan.
// ============================================================================
__global__ __launch_bounds__(256) void k3a_compact(
    const float* __restrict__ enc, const float* __restrict__ c_a,
    const float* __restrict__ c_b, const int* __restrict__ fire_t,
    const int* __restrict__ n_fired, float* __restrict__ compact)
{
    const int b = blockIdx.y;
    const int k = blockIdx.x;
    if (k >= n_fired[b]) return;
    const int tend = fire_t[b * MAXF + k];
    const int tprev = (k == 0) ? -1 : fire_t[b * MAXF + k - 1];
    const int tid = threadIdx.x;

    float a0 = 0.f, a1 = 0.f, a2 = 0.f, a3 = 0.f;
    const int tstart = (tprev < 0) ? 0 : tprev;
    for (int t = tstart; t <= tend; t++) {
        float coef = (t == tprev) ? c_b[b * TLEN + t] : c_a[b * TLEN + t];
        const float* e = enc + ((size_t)b * TLEN + t) * CDIM;
        a0 += coef * e[tid];
        a1 += coef * e[tid + 256];
        a2 += coef * e[tid + 512];
        a3 += coef * e[tid + 768];
    }
    float* dst = compact + ((size_t)b * MAXF + k) * CDIM;
    dst[tid] = a0;
    dst[tid + 256] = a1;
    dst[tid + 512] = a2;
    dst[tid + 768] = a3;
}

// ============================================================================
// Kernel 3b: cif_outputs[b, j, o] = sum_c compact[b,j,c] * Wo[o,c], j < 512.
// Same 128x128x32 tile as k1. Rows >= n_fired masked to 0; tiles fully past
// n_fired skipped (d_out pre-zeroed). Grid (4 j-tiles, 4 o-tiles, 16 b).
// ============================================================================
__global__ __launch_bounds__(256) void k3b_outproj(
    const float* __restrict__ compact, const float* __restrict__ Wo,
    const int* __restrict__ n_fired, float* __restrict__ out0)
{
    __shared__ float As[32][128];
    __shared__ float Bs[32][128];

    const int b = blockIdx.z;
    const int nf = n_fired[b];
    const int j0 = blockIdx.x * 128;
    if (j0 >= nf) return;
    const int o0 = blockIdx.y * 128;
    const int tid = threadIdx.x;
    const int tx = tid & 15, ty = tid >> 4;
    const int lr = tid & 127, lh = tid >> 7;

    float acc[8][8];
#pragma unroll
    for (int i = 0; i < 8; i++)
#pragma unroll
        for (int j = 0; j < 8; j++) acc[i][j] = 0.f;

    const bool avalid = (j0 + lr) < nf;
    const float* abase = compact + ((size_t)b * MAXF + j0 + lr) * CDIM + lh * 16;
    const float* bbase = Wo + (size_t)(o0 + lr) * CDIM + lh * 16;

    for (int k0 = 0; k0 < CDIM; k0 += 32) {
        float av[16], bv[16];
#pragma unroll
        for (int j = 0; j < 4; j++) {
            if (avalid) {
                *(float4*)&av[j * 4] = *(const float4*)(abase + k0 + j * 4);
            } else {
                av[j * 4] = 0.f; av[j * 4 + 1] = 0.f;
                av[j * 4 + 2] = 0.f; av[j * 4 + 3] = 0.f;
            }
            *(float4*)&bv[j * 4] = *(const float4*)(bbase + k0 + j * 4);
        }
        __syncthreads();
#pragma unroll
        for (int j = 0; j < 16; j++) {
            As[lh * 16 + j][lr] = av[j];
            Bs[lh * 16 + j][lr] = bv[j];
        }
        __syncthreads();
#pragma unroll 8
        for (int kk = 0; kk < 32; kk++) {
            float a[8], bb[8];
            *(float4*)&a[0] = *(const float4*)&As[kk][tx * 4];
            *(float4*)&a[4] = *(const float4*)&As[kk][tx * 4 + 64];
            *(float4*)&bb[0] = *(const float4*)&Bs[kk][ty * 4];
            *(float4*)&bb[4] = *(const float4*)&Bs[kk][ty * 4 + 64];
#pragma unroll
            for (int i = 0; i < 8; i++)
#pragma unroll
                for (int j = 0; j < 8; j++)
                    acc[i][j] += a[i] * bb[j];
        }
    }

#pragma unroll
    for (int i = 0; i < 8; i++) {
        int j = j0 + tx * 4 + (i & 3) + (i >> 2) * 64;
        float* outp = out0 + ((size_t)b * TLEN + j) * OUTDIM + o0 + ty * 4;
        float4 v0 = make_float4(acc[i][0], acc[i][1], acc[i][2], acc[i][3]);
        float4 v1 = make_float4(acc[i][4], acc[i][5], acc[i][6], acc[i][7]);
        *(float4*)outp = v0;
        *(float4*)(outp + 64) = v1;
    }
}

// ============================================================================
// Host launch
// ============================================================================
extern "C" void kernel_launch(void* const* d_in, const int* in_sizes, int n_in,
                              void* d_out, int out_size, void* d_ws, size_t ws_size,
                              hipStream_t stream)
{
    const float* enc = (const float*)d_in[0];   // [16,2048,1024]
    const int* in_len = (const int*)d_in[1];    // [16]
    const int* tgt_len = (const int*)d_in[2];   // [16]
    const float* Wd = (const float*)d_in[3];    // [1024,1024]
    const float* bd = (const float*)d_in[4];    // [1024]
    const float* Wp = (const float*)d_in[5];    // [1024]
    const float* bp = (const float*)d_in[6];    // [1]
    const float* Wo = (const float*)d_in[7];    // [512,1024]

    char* ws = (char*)d_ws;
    float* g = (float*)ws;                         // 32768 f32  = 128KB
    float* c_a = (float*)(ws + 131072);            // 32768 f32
    float* c_b = (float*)(ws + 262144);            // 32768 f32
    int* fire_t = (int*)(ws + 393216);             // 16*512 i32
    int* n_fired = (int*)(ws + 425984);            // 16 i32
    float* compact = (float*)(ws + 524288);        // 16*512*1024 f32 = 32MB

    float* out0 = (float*)d_out;                              // [16,2048,512]
    float* out_mask = out0 + (size_t)BSZ * TLEN * OUTDIM;     // [16,2048]
    float* out_dur = out_mask + (size_t)BSZ * TLEN;           // [16,2048]
    float* out_qty = out_dur + (size_t)BSZ * TLEN;            // [16]

    hipMemsetAsync(g, 0, 131072, stream);
    hipMemsetAsync(d_out, 0, (size_t)out_size * 4, stream);

    k1_weight_gemm<<<dim3(256, 8), 256, 0, stream>>>(enc, Wd, bd, Wp, g);
    k2_scan<<<BSZ, 256, 0, stream>>>(g, in_len, tgt_len, bp, c_a, c_b,
                                     fire_t, n_fired, out_mask, out_dur, out_qty);
    k3a_compact<<<dim3(MAXF, BSZ), 256, 0, stream>>>(enc, c_a, c_b, fire_t,
                                                     n_fired, compact);
    k3b_outproj<<<dim3(4, 4, BSZ), 256, 0, stream>>>(compact, Wo, n_fired, out0);
}

// Round 2
// 878.596 us; speedup vs baseline: 1.4292x; 1.4292x over previous
//
#include <hip/hip_runtime.h>
#include <cstdint>
#include <cstddef>

#define BSZ 16
#define TLEN 2048
#define CDIM 1024
#define DUDIM 1024
#define OUTDIM 512
#define MAXF 512

typedef short bf16x8 __attribute__((ext_vector_type(8)));
typedef float f32x16 __attribute__((ext_vector_type(16)));

// ============================================================================
// Kernel 1: g[row] = sum_du Wp[du] * relu( enc[row,:] . Wd[du,:] + bd[du] )
// Split-bf16 MFMA: each fp32 a = a0+a1+a2 (EXACT bitwise split into 3 bf16).
// 6 MFMA passes (i+j<=2) give relative error ~2^-26 < fp32 rounding noise.
// Block 128x128, BK=32 fp32, 4 waves each computing 64x64 via 2x2 of 32x32x16.
// LDS planes chunk-major [kchunk(16B)][row] -> baseline-conflict b128 R/W.
// ============================================================================
__global__ __launch_bounds__(256, 2) void k1_weight_gemm(
    const float* __restrict__ enc, const float* __restrict__ Wd,
    const float* __restrict__ bd, const float* __restrict__ Wp,
    float* __restrict__ g)
{
    // 6 planes (A0,A1,A2,B0,B1,B2), each 4 chunks x 2048B = 8KB (4096 shorts)
    __shared__ __align__(16) short lds[24576];

    const int tid = threadIdx.x;
    const int lane = tid & 63;
    const int wv = tid >> 6;
    const int l5 = lane & 31;
    const int hi = lane >> 5;
    const int mtb = (wv & 1) * 64;
    const int ntb = (wv >> 1) * 64;

    const long row0 = (long)blockIdx.x * 128;
    const int du0 = blockIdx.y * 128;

    // staging: thread t loads row r = t>>1, k-half h = t&1 (16 floats)
    const int sr = tid >> 1;
    const int sh = tid & 1;
    const float* aptr = enc + (row0 + sr) * (long)CDIM + sh * 16;
    const float* bptr = Wd + (long)(du0 + sr) * CDIM + sh * 16;

    f32x16 acc[2][2];
#pragma unroll
    for (int mt = 0; mt < 2; mt++)
#pragma unroll
        for (int nt = 0; nt < 2; nt++)
#pragma unroll
            for (int r = 0; r < 16; r++) acc[mt][nt][r] = 0.f;

    float fa[16], fb[16];
#pragma unroll
    for (int j = 0; j < 4; j++) {
        *(float4*)&fa[j * 4] = *(const float4*)(aptr + j * 4);
        *(float4*)&fb[j * 4] = *(const float4*)(bptr + j * 4);
    }

    for (int kt = 0; kt < 32; ++kt) {
        // exact 3-way split of this thread's 16 A floats and 16 B floats,
        // packed into uint4 (8 bf16) per chunk per plane
        uint4 wa[3][2], wb[3][2];
#pragma unroll
        for (int c = 0; c < 2; c++) {
            unsigned ua0[8], ua1[8], ua2[8], ub0[8], ub1[8], ub2[8];
#pragma unroll
            for (int j = 0; j < 8; j++) {
                {
                    float a = fa[c * 8 + j];
                    unsigned u = __float_as_uint(a) & 0xffff0000u;
                    float r1 = a - __uint_as_float(u);
                    unsigned u1 = __float_as_uint(r1) & 0xffff0000u;
                    float r2 = r1 - __uint_as_float(u1);
                    ua0[j] = u; ua1[j] = u1; ua2[j] = __float_as_uint(r2);
                }
                {
                    float b = fb[c * 8 + j];
                    unsigned u = __float_as_uint(b) & 0xffff0000u;
                    float r1 = b - __uint_as_float(u);
                    unsigned u1 = __float_as_uint(r1) & 0xffff0000u;
                    float r2 = r1 - __uint_as_float(u1);
                    ub0[j] = u; ub1[j] = u1; ub2[j] = __float_as_uint(r2);
                }
            }
#define PACK(lo, hiw) (((lo) >> 16) | ((hiw) & 0xffff0000u))
            wa[0][c] = make_uint4(PACK(ua0[0], ua0[1]), PACK(ua0[2], ua0[3]),
                                  PACK(ua0[4], ua0[5]), PACK(ua0[6], ua0[7]));
            wa[1][c] = make_uint4(PACK(ua1[0], ua1[1]), PACK(ua1[2], ua1[3]),
                                  PACK(ua1[4], ua1[5]), PACK(ua1[6], ua1[7]));
            wa[2][c] = make_uint4(PACK(ua2[0], ua2[1]), PACK(ua2[2], ua2[3]),
                                  PACK(ua2[4], ua2[5]), PACK(ua2[6], ua2[7]));
            wb[0][c] = make_uint4(PACK(ub0[0], ub0[1]), PACK(ub0[2], ub0[3]),
                                  PACK(ub0[4], ub0[5]), PACK(ub0[6], ub0[7]));
            wb[1][c] = make_uint4(PACK(ub1[0], ub1[1]), PACK(ub1[2], ub1[3]),
                                  PACK(ub1[4], ub1[5]), PACK(ub1[6], ub1[7]));
            wb[2][c] = make_uint4(PACK(ub2[0], ub2[1]), PACK(ub2[2], ub2[3]),
                                  PACK(ub2[4], ub2[5]), PACK(ub2[6], ub2[7]));
#undef PACK
        }

        __syncthreads();   // all waves finished reading LDS of previous k-tile
#pragma unroll
        for (int p = 0; p < 3; p++) {
#pragma unroll
            for (int c = 0; c < 2; c++) {
                *(uint4*)&lds[p * 4096 + (2 * sh + c) * 1024 + sr * 8] = wa[p][c];
                *(uint4*)&lds[12288 + p * 4096 + (2 * sh + c) * 1024 + sr * 8] = wb[p][c];
            }
        }
        __syncthreads();

        if (kt < 31) {
#pragma unroll
            for (int j = 0; j < 4; j++) {
                *(float4*)&fa[j * 4] = *(const float4*)(aptr + (kt + 1) * 32 + j * 4);
                *(float4*)&fb[j * 4] = *(const float4*)(bptr + (kt + 1) * 32 + j * 4);
            }
        }

#pragma unroll
        for (int ks = 0; ks < 2; ks++) {
            bf16x8 A[2][3], B[2][3];
#pragma unroll
            for (int mt = 0; mt < 2; mt++)
#pragma unroll
                for (int s = 0; s < 3; s++)
                    A[mt][s] = *(const bf16x8*)&lds[s * 4096 + (ks * 2 + hi) * 1024 +
                                                   (mtb + mt * 32 + l5) * 8];
#pragma unroll
            for (int nt = 0; nt < 2; nt++)
#pragma unroll
                for (int s = 0; s < 3; s++)
                    B[nt][s] = *(const bf16x8*)&lds[12288 + s * 4096 + (ks * 2 + hi) * 1024 +
                                                    (ntb + nt * 32 + l5) * 8];
#pragma unroll
            for (int mt = 0; mt < 2; mt++)
#pragma unroll
                for (int nt = 0; nt < 2; nt++) {
                    f32x16 a = acc[mt][nt];
                    a = __builtin_amdgcn_mfma_f32_32x32x16_bf16(A[mt][0], B[nt][0], a, 0, 0, 0);
                    a = __builtin_amdgcn_mfma_f32_32x32x16_bf16(A[mt][0], B[nt][1], a, 0, 0, 0);
                    a = __builtin_amdgcn_mfma_f32_32x32x16_bf16(A[mt][1], B[nt][0], a, 0, 0, 0);
                    a = __builtin_amdgcn_mfma_f32_32x32x16_bf16(A[mt][0], B[nt][2], a, 0, 0, 0);
                    a = __builtin_amdgcn_mfma_f32_32x32x16_bf16(A[mt][1], B[nt][1], a, 0, 0, 0);
                    a = __builtin_amdgcn_mfma_f32_32x32x16_bf16(A[mt][2], B[nt][0], a, 0, 0, 0);
                    acc[mt][nt] = a;
                }
        }
    }

    // epilogue: h = relu(acc + bd[n]); partial g += Wp[n]*h, reduced over n
    float bdv[2], wpv[2];
#pragma unroll
    for (int nt = 0; nt < 2; nt++) {
        int n = du0 + ntb + nt * 32 + l5;
        bdv[nt] = bd[n];
        wpv[nt] = Wp[n];
    }
    float pm[2][16];
#pragma unroll
    for (int mt = 0; mt < 2; mt++)
#pragma unroll
        for (int r = 0; r < 16; r++) {
            float s = 0.f;
#pragma unroll
            for (int nt = 0; nt < 2; nt++) {
                float h = acc[mt][nt][r] + bdv[nt];
                h = h > 0.f ? h : 0.f;
                s += wpv[nt] * h;
            }
            // butterfly-reduce over the 32 lanes of this half-wave (64 n total)
            s += __shfl_xor(s, 1);
            s += __shfl_xor(s, 2);
            s += __shfl_xor(s, 4);
            s += __shfl_xor(s, 8);
            s += __shfl_xor(s, 16);
            pm[mt][r] = s;
        }
    // lane l5 selects value (mt = l5>>4, r = l5&15); rows differ per half-wave
    float out = 0.f;
#pragma unroll
    for (int mt = 0; mt < 2; mt++)
#pragma unroll
        for (int r = 0; r < 16; r++)
            if (l5 == mt * 16 + r) out = pm[mt][r];
    const int mt_sel = l5 >> 4;
    const int r_sel = l5 & 15;
    const int row = mtb + mt_sel * 32 + (r_sel & 3) + 8 * (r_sel >> 2) + 4 * hi;
    atomicAdd(&g[row0 + row], out);
}

// ============================================================================
// Kernel 2: per-batch sigmoid + masked sum + scale + sequential CIF scan.
// ============================================================================
__global__ __launch_bounds__(256) void k2_scan(
    const float* __restrict__ g, const int* __restrict__ in_len,
    const int* __restrict__ tgt_len, const float* __restrict__ bp,
    float* __restrict__ c_a, float* __restrict__ c_b,
    int* __restrict__ fire_t, int* __restrict__ n_fired,
    float* __restrict__ out_mask, float* __restrict__ out_dur,
    float* __restrict__ out_qty)
{
    __shared__ float w[TLEN];
    __shared__ int fires[MAXF];
    __shared__ float ssum[256];
    __shared__ float s_scale;
    __shared__ int s_nf;

    const int b = blockIdx.x;
    const int tid = threadIdx.x;
    const int len = in_len[b];
    const float bpv = bp[0];

    float local = 0.f;
    for (int t = tid; t < TLEN; t += 256) {
        float gv = g[b * TLEN + t] + bpv;
        float s = 1.f / (1.f + expf(-gv));
        float ow = (t < len) ? s : 0.f;
        w[t] = ow;
        local += ow;
    }
    ssum[tid] = local;
    __syncthreads();
    for (int st = 128; st > 0; st >>= 1) {
        if (tid < st) ssum[tid] += ssum[tid + st];
        __syncthreads();
    }
    if (tid == 0) {
        float org_sum = ssum[0];
        out_qty[b] = org_sum;
        s_scale = (float)tgt_len[b] / (org_sum + 1e-8f);
    }
    __syncthreads();
    float scale = s_scale;
    for (int t = tid; t < TLEN; t += 256) w[t] *= scale;
    __syncthreads();

    if (tid == 0) {
        float accw = 0.f;
        int k = 0;
        for (int t = 0; t < len; t++) {
            float wt = w[t];
            float aw = accw + wt;
            if (aw >= 1.0f) {
                float remained = 1.f - accw;      // exact reference order
                c_a[b * TLEN + t] = remained;
                c_b[b * TLEN + t] = wt - remained;
                if (k < MAXF) fires[k] = t;
                k++;
                accw = wt - remained;
            } else {
                c_a[b * TLEN + t] = wt;
                c_b[b * TLEN + t] = 0.f;
                accw = aw;
            }
        }
        s_nf = (k < MAXF) ? k : MAXF;
        n_fired[b] = s_nf;
    }
    __syncthreads();

    const int nf = s_nf;
    for (int j = tid; j < nf; j += 256) {
        int tj = fires[j];
        fire_t[b * MAXF + j] = tj;
        out_mask[b * TLEN + j] = 1.0f;
        int prev = (j == 0) ? 0 : fires[j - 1];
        out_dur[b * TLEN + j] = (float)(tj - prev);
    }
    if (tid == 0 && nf == 0) out_mask[b * TLEN] = 1.0f;  // reference fallback
}

// ============================================================================
// Kernel 3a: compact fired frames (segmented weighted sums, ascending t).
// ============================================================================
__global__ __launch_bounds__(256) void k3a_compact(
    const float* __restrict__ enc, const float* __restrict__ c_a,
    const float* __restrict__ c_b, const int* __restrict__ fire_t,
    const int* __restrict__ n_fired, float* __restrict__ compact)
{
    const int b = blockIdx.y;
    const int k = blockIdx.x;
    if (k >= n_fired[b]) return;
    const int tend = fire_t[b * MAXF + k];
    const int tprev = (k == 0) ? -1 : fire_t[b * MAXF + k - 1];
    const int tid = threadIdx.x;

    float a0 = 0.f, a1 = 0.f, a2 = 0.f, a3 = 0.f;
    const int tstart = (tprev < 0) ? 0 : tprev;
    for (int t = tstart; t <= tend; t++) {
        float coef = (t == tprev) ? c_b[b * TLEN + t] : c_a[b * TLEN + t];
        const float* e = enc + ((size_t)b * TLEN + t) * CDIM;
        a0 += coef * e[tid];
        a1 += coef * e[tid + 256];
        a2 += coef * e[tid + 512];
        a3 += coef * e[tid + 768];
    }
    float* dst = compact + ((size_t)b * MAXF + k) * CDIM;
    dst[tid] = a0;
    dst[tid + 256] = a1;
    dst[tid + 512] = a2;
    dst[tid + 768] = a3;
}

// ============================================================================
// Kernel 3b: output projection, fp32 128x128x32 tile (unchanged).
// ============================================================================
__global__ __launch_bounds__(256) void k3b_outproj(
    const float* __restrict__ compact, const float* __restrict__ Wo,
    const int* __restrict__ n_fired, float* __restrict__ out0)
{
    __shared__ float As[32][128];
    __shared__ float Bs[32][128];

    const int b = blockIdx.z;
    const int nf = n_fired[b];
    const int j0 = blockIdx.x * 128;
    if (j0 >= nf) return;
    const int o0 = blockIdx.y * 128;
    const int tid = threadIdx.x;
    const int tx = tid & 15, ty = tid >> 4;
    const int lr = tid & 127, lh = tid >> 7;

    float acc[8][8];
#pragma unroll
    for (int i = 0; i < 8; i++)
#pragma unroll
        for (int j = 0; j < 8; j++) acc[i][j] = 0.f;

    const bool avalid = (j0 + lr) < nf;
    const float* abase = compact + ((size_t)b * MAXF + j0 + lr) * CDIM + lh * 16;
    const float* bbase = Wo + (size_t)(o0 + lr) * CDIM + lh * 16;

    for (int k0 = 0; k0 < CDIM; k0 += 32) {
        float av[16], bv[16];
#pragma unroll
        for (int j = 0; j < 4; j++) {
            if (avalid) {
                *(float4*)&av[j * 4] = *(const float4*)(abase + k0 + j * 4);
            } else {
                av[j * 4] = 0.f; av[j * 4 + 1] = 0.f;
                av[j * 4 + 2] = 0.f; av[j * 4 + 3] = 0.f;
            }
            *(float4*)&bv[j * 4] = *(const float4*)(bbase + k0 + j * 4);
        }
        __syncthreads();
#pragma unroll
        for (int j = 0; j < 16; j++) {
            As[lh * 16 + j][lr] = av[j];
            Bs[lh * 16 + j][lr] = bv[j];
        }
        __syncthreads();
#pragma unroll 8
        for (int kk = 0; kk < 32; kk++) {
            float a[8], bb[8];
            *(float4*)&a[0] = *(const float4*)&As[kk][tx * 4];
            *(float4*)&a[4] = *(const float4*)&As[kk][tx * 4 + 64];
            *(float4*)&bb[0] = *(const float4*)&Bs[kk][ty * 4];
            *(float4*)&bb[4] = *(const float4*)&Bs[kk][ty * 4 + 64];
#pragma unroll
            for (int i = 0; i < 8; i++)
#pragma unroll
                for (int j = 0; j < 8; j++)
                    acc[i][j] += a[i] * bb[j];
        }
    }

#pragma unroll
    for (int i = 0; i < 8; i++) {
        int j = j0 + tx * 4 + (i & 3) + (i >> 2) * 64;
        float* outp = out0 + ((size_t)b * TLEN + j) * OUTDIM + o0 + ty * 4;
        float4 v0 = make_float4(acc[i][0], acc[i][1], acc[i][2], acc[i][3]);
        float4 v1 = make_float4(acc[i][4], acc[i][5], acc[i][6], acc[i][7]);
        *(float4*)outp = v0;
        *(float4*)(outp + 64) = v1;
    }
}

// ============================================================================
// Host launch
// ============================================================================
extern "C" void kernel_launch(void* const* d_in, const int* in_sizes, int n_in,
                              void* d_out, int out_size, void* d_ws, size_t ws_size,
                              hipStream_t stream)
{
    const float* enc = (const float*)d_in[0];   // [16,2048,1024]
    const int* in_len = (const int*)d_in[1];    // [16]
    const int* tgt_len = (const int*)d_in[2];   // [16]
    const float* Wd = (const float*)d_in[3];    // [1024,1024]
    const float* bd = (const float*)d_in[4];    // [1024]
    const float* Wp = (const float*)d_in[5];    // [1024]
    const float* bp = (const float*)d_in[6];    // [1]
    const float* Wo = (const float*)d_in[7];    // [512,1024]

    char* ws = (char*)d_ws;
    float* g = (float*)ws;                         // 32768 f32  = 128KB
    float* c_a = (float*)(ws + 131072);            // 32768 f32
    float* c_b = (float*)(ws + 262144);            // 32768 f32
    int* fire_t = (int*)(ws + 393216);             // 16*512 i32
    int* n_fired = (int*)(ws + 425984);            // 16 i32
    float* compact = (float*)(ws + 524288);        // 16*512*1024 f32 = 32MB

    float* out0 = (float*)d_out;                              // [16,2048,512]
    float* out_mask = out0 + (size_t)BSZ * TLEN * OUTDIM;     // [16,2048]
    float* out_dur = out_mask + (size_t)BSZ * TLEN;           // [16,2048]
    float* out_qty = out_dur + (size_t)BSZ * TLEN;            // [16]

    hipMemsetAsync(g, 0, 131072, stream);
    hipMemsetAsync(d_out, 0, (size_t)out_size * 4, stream);

    k1_weight_gemm<<<dim3(256, 8), 256, 0, stream>>>(enc, Wd, bd, Wp, g);
    k2_scan<<<BSZ, 256, 0, stream>>>(g, in_len, tgt_len, bp, c_a, c_b,
                                     fire_t, n_fired, out_mask, out_dur, out_qty);
    k3a_compact<<<dim3(MAXF, BSZ), 256, 0, stream>>>(enc, c_a, c_b, fire_t,
                                                     n_fired, compact);
    k3b_outproj<<<dim3(4, 4, BSZ), 256, 0, stream>>>(compact, Wo, n_fired, out0);
}

// Round 4
// 644.939 us; speedup vs baseline: 1.9469x; 1.3623x over previous
//
#include <hip/hip_runtime.h>
#include <cstdint>
#include <cstddef>

#define BSZ 16
#define TLEN 2048
#define CDIM 1024
#define OUTDIM 512
#define MAXF 512

typedef _Float16 f16x8 __attribute__((ext_vector_type(8)));
typedef _Float16 f16x4 __attribute__((ext_vector_type(4)));
typedef float f32x16 __attribute__((ext_vector_type(16)));

__device__ __forceinline__ void gl_lds16(const void* g, void* l) {
    __builtin_amdgcn_global_load_lds(
        (const __attribute__((address_space(1))) void*)g,
        (__attribute__((address_space(3))) void*)l, 16, 0, 0);
}

// exact 2-term fp16 split: a = h0 + h1 * 2^-11  (h1 pre-scaled by 2^11 so it
// stays in fp16 normal range; dropped residual <= 2^-22 |a|)
struct h2pair { _Float16 h0, h1; };
__device__ __forceinline__ h2pair split2(float a) {
    h2pair o;
    o.h0 = (_Float16)a;
    float r = a - (float)o.h0;       // exact (Sterbenz)
    o.h1 = (_Float16)(r * 2048.0f);
    return o;
}

// ============================================================================
// k0a: split Wd into 2 fp16 planes in k1's TILED layout:
// plane[(dut*32+ktl)*4096 + (chunk*128 + n)*8 + j], chunk = k-16B-group (8 halves)
// ============================================================================
__global__ __launch_bounds__(128) void k0a_split_wd(
    const float* __restrict__ Wd, _Float16* __restrict__ B0,
    _Float16* __restrict__ B1)
{
    const int dut = blockIdx.x;     // 8
    const int ktl = blockIdx.y;     // 32
    const int r = threadIdx.x;      // 128 (n within tile)
    const float* src = Wd + (size_t)(dut * 128 + r) * CDIM + ktl * 32;
    float v[32];
#pragma unroll
    for (int j = 0; j < 8; j++) *(float4*)&v[j * 4] = *(const float4*)(src + j * 4);
    const size_t tb = (size_t)(dut * 32 + ktl) * 4096;
#pragma unroll
    for (int c = 0; c < 4; c++) {
        f16x8 h0, h1;
#pragma unroll
        for (int j = 0; j < 8; j++) {
            h2pair s = split2(v[c * 8 + j]);
            h0[j] = s.h0;
            h1[j] = s.h1;
        }
        *(f16x8*)&B0[tb + (c * 128 + r) * 8] = h0;
        *(f16x8*)&B1[tb + (c * 128 + r) * 8] = h1;
    }
}

// ============================================================================
// k0c: split Wo into 2 fp16 planes, simple row-major [o][k]
// ============================================================================
__global__ __launch_bounds__(256) void k0c_split_wo(
    const float* __restrict__ Wo, _Float16* __restrict__ W0,
    _Float16* __restrict__ W1)
{
    const int i = (blockIdx.x * 256 + threadIdx.x) * 4;   // 512 blocks -> 524288
    float4 v = *(const float4*)(Wo + i);
    f16x4 h0, h1;
    h2pair s0 = split2(v.x); h0[0] = s0.h0; h1[0] = s0.h1;
    h2pair s1 = split2(v.y); h0[1] = s1.h0; h1[1] = s1.h1;
    h2pair s2 = split2(v.z); h0[2] = s2.h0; h1[2] = s2.h1;
    h2pair s3 = split2(v.w); h0[3] = s3.h0; h1[3] = s3.h1;
    *(f16x4*)&W0[i] = h0;
    *(f16x4*)&W1[i] = h1;
}

// ============================================================================
// k1: g[row] = sum_du Wp[du]*relu(enc[row,:].Wd[du,:] + bd[du])
// fp16 2-term split, 3 MFMA products (A0B0 -> acc; A0B1'+A1'B0 -> acc_c),
// final = acc + acc_c * 2^-11. 128x128x32 tile, 4 waves x (64x64 via 2x2 of
// 32x32x16). A split on the fly (lane load + ds_write); B via global_load_lds
// from k0a's tiled planes. Grid swizzle: du = bx&7 for A-tile L2 reuse.
// ============================================================================
__global__ __launch_bounds__(256, 2) void k1_weight_gemm(
    const float* __restrict__ enc, const _Float16* __restrict__ BT0,
    const _Float16* __restrict__ BT1, const float* __restrict__ bd,
    const float* __restrict__ Wp, float* __restrict__ g)
{
    __shared__ __align__(16) _Float16 lds[16384];  // A0|A1|B0|B1 quarters of 4096

    const int tid = threadIdx.x;
    const int lane = tid & 63;
    const int wv = tid >> 6;
    const int l5 = lane & 31;
    const int hi = lane >> 5;
    const int mtb = (wv & 1) * 64;
    const int ntb = (wv >> 1) * 64;

    const int bx = blockIdx.x;
    const int dut = bx & 7;
    const long row0 = (long)(bx >> 3) * 128;
    const int du0 = dut * 128;

    const int sr = tid >> 1;          // A staging row
    const int sh = tid & 1;           // A staging k-half (16 floats)
    const float* aptr = enc + (row0 + sr) * (long)CDIM + sh * 16;

    const _Float16* btile = ((wv >> 1) ? BT1 : BT0) + (size_t)dut * 32 * 4096;
    const int bh = wv & 1;            // which half of the B tile this wave stages
    _Float16* blds = &lds[8192 + (wv >> 1) * 4096 + bh * 2048];

    f32x16 acc[2][2], accc[2][2];
#pragma unroll
    for (int mt = 0; mt < 2; mt++)
#pragma unroll
        for (int nt = 0; nt < 2; nt++)
#pragma unroll
            for (int r = 0; r < 16; r++) { acc[mt][nt][r] = 0.f; accc[mt][nt][r] = 0.f; }

    float fa[16];
#pragma unroll
    for (int j = 0; j < 4; j++) *(float4*)&fa[j * 4] = *(const float4*)(aptr + j * 4);

    for (int kt = 0; kt < 32; ++kt) {
        // split this thread's 16 A floats into 2 chunks x 2 planes
        f16x8 va0[2], va1[2];
#pragma unroll
        for (int c = 0; c < 2; c++)
#pragma unroll
            for (int j = 0; j < 8; j++) {
                h2pair s = split2(fa[c * 8 + j]);
                va0[c][j] = s.h0;
                va1[c][j] = s.h1;
            }

        __syncthreads();   // all waves done reading previous k-tile
#pragma unroll
        for (int c = 0; c < 2; c++) {
            *(f16x8*)&lds[((sh * 2 + c) * 128 + sr) * 8] = va0[c];
            *(f16x8*)&lds[4096 + ((sh * 2 + c) * 128 + sr) * 8] = va1[c];
        }
#pragma unroll
        for (int c = 0; c < 4; c++) {
            gl_lds16(btile + (size_t)kt * 4096 + (bh * 256 + c * 64 + lane) * 8,
                     blds + c * 512);
        }
        __syncthreads();   // drains vmcnt+lgkm: tiles ready

        if (kt < 31) {
#pragma unroll
            for (int j = 0; j < 4; j++)
                *(float4*)&fa[j * 4] = *(const float4*)(aptr + (kt + 1) * 32 + j * 4);
        }

#pragma unroll
        for (int ks = 0; ks < 2; ks++) {
            const int ch = ks * 2 + hi;
            f16x8 A0[2], A1[2], B0[2], B1[2];
#pragma unroll
            for (int mt = 0; mt < 2; mt++) {
                const int row = mtb + mt * 32 + l5;
                A0[mt] = *(const f16x8*)&lds[(ch * 128 + row) * 8];
                A1[mt] = *(const f16x8*)&lds[4096 + (ch * 128 + row) * 8];
            }
#pragma unroll
            for (int nt = 0; nt < 2; nt++) {
                const int row = ntb + nt * 32 + l5;
                B0[nt] = *(const f16x8*)&lds[8192 + (ch * 128 + row) * 8];
                B1[nt] = *(const f16x8*)&lds[12288 + (ch * 128 + row) * 8];
            }
#pragma unroll
            for (int mt = 0; mt < 2; mt++)
#pragma unroll
                for (int nt = 0; nt < 2; nt++) {
                    acc[mt][nt] = __builtin_amdgcn_mfma_f32_32x32x16_f16(
                        A0[mt], B0[nt], acc[mt][nt], 0, 0, 0);
                    accc[mt][nt] = __builtin_amdgcn_mfma_f32_32x32x16_f16(
                        A0[mt], B1[nt], accc[mt][nt], 0, 0, 0);
                    accc[mt][nt] = __builtin_amdgcn_mfma_f32_32x32x16_f16(
                        A1[mt], B0[nt], accc[mt][nt], 0, 0, 0);
                }
        }
    }

    // epilogue: h = relu(acc_total + bd[n]); g += Wp[n]*h reduced over n
    float bdv[2], wpv[2];
#pragma unroll
    for (int nt = 0; nt < 2; nt++) {
        int n = du0 + ntb + nt * 32 + l5;
        bdv[nt] = bd[n];
        wpv[nt] = Wp[n];
    }
    float pm[2][16];
#pragma unroll
    for (int mt = 0; mt < 2; mt++)
#pragma unroll
        for (int r = 0; r < 16; r++) {
            float s = 0.f;
#pragma unroll
            for (int nt = 0; nt < 2; nt++) {
                float h = acc[mt][nt][r] + 4.8828125e-4f * accc[mt][nt][r] + bdv[nt];
                h = h > 0.f ? h : 0.f;
                s += wpv[nt] * h;
            }
            s += __shfl_xor(s, 1);
            s += __shfl_xor(s, 2);
            s += __shfl_xor(s, 4);
            s += __shfl_xor(s, 8);
            s += __shfl_xor(s, 16);
            pm[mt][r] = s;
        }
    float out = 0.f;
#pragma unroll
    for (int mt = 0; mt < 2; mt++)
#pragma unroll
        for (int r = 0; r < 16; r++)
            if (l5 == mt * 16 + r) out = pm[mt][r];
    const int mt_sel = l5 >> 4;
    const int r_sel = l5 & 15;
    const int row = mtb + mt_sel * 32 + (r_sel & 3) + 8 * (r_sel >> 2) + 4 * hi;
    atomicAdd(&g[row0 + row], out);
}

// ============================================================================
// k2: per-batch sigmoid + masked sum + scale + branchless sequential scan.
// c_a/c_b buffered in LDS, bulk-copied; exact reference fp32 op order.
// ============================================================================
__global__ __launch_bounds__(256) void k2_scan(
    const float* __restrict__ g, const int* __restrict__ in_len,
    const int* __restrict__ tgt_len, const float* __restrict__ bp,
    float* __restrict__ c_a, float* __restrict__ c_b,
    int* __restrict__ fire_t, int* __restrict__ n_fired,
    float* __restrict__ out_mask, float* __restrict__ out_dur,
    float* __restrict__ out_qty)
{
    __shared__ float w[TLEN];
    __shared__ float ca[TLEN];
    __shared__ float cb[TLEN];
    __shared__ int fires[MAXF];
    __shared__ float ssum[256];
    __shared__ float s_scale;
    __shared__ int s_nf;

    const int b = blockIdx.x;
    const int tid = threadIdx.x;
    const int len = in_len[b];
    const float bpv = bp[0];

    float local = 0.f;
    for (int t = tid; t < TLEN; t += 256) {
        float gv = g[b * TLEN + t] + bpv;
        float s = 1.f / (1.f + expf(-gv));
        float ow = (t < len) ? s : 0.f;
        w[t] = ow;
        local += ow;
    }
    ssum[tid] = local;
    __syncthreads();
    for (int st = 128; st > 0; st >>= 1) {
        if (tid < st) ssum[tid] += ssum[tid + st];
        __syncthreads();
    }
    if (tid == 0) {
        float org_sum = ssum[0];
        out_qty[b] = org_sum;
        s_scale = (float)tgt_len[b] / (org_sum + 1e-8f);
    }
    __syncthreads();
    float scale = s_scale;
    for (int t = tid; t < TLEN; t += 256) w[t] *= scale;
    __syncthreads();

    if (tid == 0) {
        float accw = 0.f;
        int k = 0;
        for (int t = 0; t < len; t++) {
            float wt = w[t];
            float aw = accw + wt;
            bool f = (aw >= 1.0f);
            float rem = 1.0f - accw;          // exact reference order
            float fb = wt - rem;
            ca[t] = f ? rem : wt;
            cb[t] = f ? fb : 0.f;
            fires[k & (MAXF - 1)] = t;        // only "sticks" when f
            k += f ? 1 : 0;
            accw = f ? fb : aw;
        }
        s_nf = (k < MAXF) ? k : MAXF;
        n_fired[b] = s_nf;
    }
    __syncthreads();

    for (int t = tid; t < len; t += 256) {
        c_a[b * TLEN + t] = ca[t];
        c_b[b * TLEN + t] = cb[t];
    }
    const int nf = s_nf;
    for (int j = tid; j < nf; j += 256) {
        int tj = fires[j];
        fire_t[b * MAXF + j] = tj;
        out_mask[b * TLEN + j] = 1.0f;
        int prev = (j == 0) ? 0 : fires[j - 1];
        out_dur[b * TLEN + j] = (float)(tj - prev);
    }
    if (tid == 0 && nf == 0) out_mask[b * TLEN] = 1.0f;
}

// ============================================================================
// k3a: compact fired frames (segmented weighted sums, ascending t), writing
// fp16 split planes row-major [b][frame][k]; rows >= n_fired zero-filled.
// ============================================================================
__global__ __launch_bounds__(256) void k3a_compact(
    const float* __restrict__ enc, const float* __restrict__ c_a,
    const float* __restrict__ c_b, const int* __restrict__ fire_t,
    const int* __restrict__ n_fired, _Float16* __restrict__ C0,
    _Float16* __restrict__ C1)
{
    const int b = blockIdx.y;
    const int k = blockIdx.x;
    const int tid = threadIdx.x;
    _Float16* d0 = C0 + ((size_t)b * MAXF + k) * CDIM + tid * 4;
    _Float16* d1 = C1 + ((size_t)b * MAXF + k) * CDIM + tid * 4;
    if (k >= n_fired[b]) {
        f16x4 z = {(_Float16)0.f, (_Float16)0.f, (_Float16)0.f, (_Float16)0.f};
        *(f16x4*)d0 = z;
        *(f16x4*)d1 = z;
        return;
    }
    const int tend = fire_t[b * MAXF + k];
    const int tprev = (k == 0) ? -1 : fire_t[b * MAXF + k - 1];
    float ax = 0.f, ay = 0.f, az = 0.f, aw = 0.f;
    const int tstart = (tprev < 0) ? 0 : tprev;
    for (int t = tstart; t <= tend; t++) {
        float coef = (t == tprev) ? c_b[b * TLEN + t] : c_a[b * TLEN + t];
        const float4 e = *(const float4*)(enc + ((size_t)b * TLEN + t) * CDIM + tid * 4);
        ax += coef * e.x;
        ay += coef * e.y;
        az += coef * e.z;
        aw += coef * e.w;
    }
    f16x4 h0, h1;
    h2pair s0 = split2(ax); h0[0] = s0.h0; h1[0] = s0.h1;
    h2pair s1 = split2(ay); h0[1] = s1.h0; h1[1] = s1.h1;
    h2pair s2 = split2(az); h0[2] = s2.h0; h1[2] = s2.h1;
    h2pair s3 = split2(aw); h0[3] = s3.h0; h1[3] = s3.h1;
    *(f16x4*)d0 = h0;
    *(f16x4*)d1 = h1;
}

// ============================================================================
// k3b: cif_outputs[b,j,o] = compact[b,j,:].Wo[o,:] — fp16-3 MFMA, same tile
// structure as k1; staging from row-major planes via lane load + ds_write.
// ============================================================================
__global__ __launch_bounds__(256, 2) void k3b_outproj(
    const _Float16* __restrict__ C0, const _Float16* __restrict__ C1,
    const _Float16* __restrict__ W0, const _Float16* __restrict__ W1,
    const int* __restrict__ n_fired, float* __restrict__ out0)
{
    __shared__ __align__(16) _Float16 lds[16384];

    const int b = blockIdx.z;
    const int nf = n_fired[b];
    const int j0 = blockIdx.x * 128;
    if (j0 >= nf) return;
    const int o0 = blockIdx.y * 128;
    const int tid = threadIdx.x;
    const int lane = tid & 63;
    const int wv = tid >> 6;
    const int l5 = lane & 31;
    const int hi = lane >> 5;
    const int mtb = (wv & 1) * 64;
    const int ntb = (wv >> 1) * 64;

    const int sr = tid >> 1;
    const int sh = tid & 1;
    const _Float16* a0p = C0 + ((size_t)b * MAXF + j0 + sr) * CDIM + sh * 16;
    const _Float16* a1p = C1 + ((size_t)b * MAXF + j0 + sr) * CDIM + sh * 16;
    const _Float16* b0p = W0 + (size_t)(o0 + sr) * CDIM + sh * 16;
    const _Float16* b1p = W1 + (size_t)(o0 + sr) * CDIM + sh * 16;

    f32x16 acc[2][2], accc[2][2];
#pragma unroll
    for (int mt = 0; mt < 2; mt++)
#pragma unroll
        for (int nt = 0; nt < 2; nt++)
#pragma unroll
            for (int r = 0; r < 16; r++) { acc[mt][nt][r] = 0.f; accc[mt][nt][r] = 0.f; }

    f16x8 xa0[2], xa1[2], xb0[2], xb1[2];
#pragma unroll
    for (int c = 0; c < 2; c++) {
        xa0[c] = *(const f16x8*)(a0p + c * 8);
        xa1[c] = *(const f16x8*)(a1p + c * 8);
        xb0[c] = *(const f16x8*)(b0p + c * 8);
        xb1[c] = *(const f16x8*)(b1p + c * 8);
    }

    for (int kt = 0; kt < 32; ++kt) {
        __syncthreads();
#pragma unroll
        for (int c = 0; c < 2; c++) {
            *(f16x8*)&lds[((sh * 2 + c) * 128 + sr) * 8] = xa0[c];
            *(f16x8*)&lds[4096 + ((sh * 2 + c) * 128 + sr) * 8] = xa1[c];
            *(f16x8*)&lds[8192 + ((sh * 2 + c) * 128 + sr) * 8] = xb0[c];
            *(f16x8*)&lds[12288 + ((sh * 2 + c) * 128 + sr) * 8] = xb1[c];
        }
        __syncthreads();
        if (kt < 31) {
            const int o = (kt + 1) * 32;
#pragma unroll
            for (int c = 0; c < 2; c++) {
                xa0[c] = *(const f16x8*)(a0p + o + c * 8);
                xa1[c] = *(const f16x8*)(a1p + o + c * 8);
                xb0[c] = *(const f16x8*)(b0p + o + c * 8);
                xb1[c] = *(const f16x8*)(b1p + o + c * 8);
            }
        }
#pragma unroll
        for (int ks = 0; ks < 2; ks++) {
            const int ch = ks * 2 + hi;
            f16x8 A0[2], A1[2], B0[2], B1[2];
#pragma unroll
            for (int mt = 0; mt < 2; mt++) {
                const int row = mtb + mt * 32 + l5;
                A0[mt] = *(const f16x8*)&lds[(ch * 128 + row) * 8];
                A1[mt] = *(const f16x8*)&lds[4096 + (ch * 128 + row) * 8];
            }
#pragma unroll
            for (int nt = 0; nt < 2; nt++) {
                const int row = ntb + nt * 32 + l5;
                B0[nt] = *(const f16x8*)&lds[8192 + (ch * 128 + row) * 8];
                B1[nt] = *(const f16x8*)&lds[12288 + (ch * 128 + row) * 8];
            }
#pragma unroll
            for (int mt = 0; mt < 2; mt++)
#pragma unroll
                for (int nt = 0; nt < 2; nt++) {
                    acc[mt][nt] = __builtin_amdgcn_mfma_f32_32x32x16_f16(
                        A0[mt], B0[nt], acc[mt][nt], 0, 0, 0);
                    accc[mt][nt] = __builtin_amdgcn_mfma_f32_32x32x16_f16(
                        A0[mt], B1[nt], accc[mt][nt], 0, 0, 0);
                    accc[mt][nt] = __builtin_amdgcn_mfma_f32_32x32x16_f16(
                        A1[mt], B0[nt], accc[mt][nt], 0, 0, 0);
                }
        }
    }

#pragma unroll
    for (int mt = 0; mt < 2; mt++)
#pragma unroll
        for (int nt = 0; nt < 2; nt++)
#pragma unroll
            for (int r = 0; r < 16; r++) {
                float val = acc[mt][nt][r] + 4.8828125e-4f * accc[mt][nt][r];
                int m = mtb + mt * 32 + (r & 3) + 8 * (r >> 2) + 4 * hi;
                int col = o0 + ntb + nt * 32 + l5;
                out0[((size_t)b * TLEN + j0 + m) * OUTDIM + col] = val;
            }
}

// ============================================================================
// Host launch
// ============================================================================
extern "C" void kernel_launch(void* const* d_in, const int* in_sizes, int n_in,
                              void* d_out, int out_size, void* d_ws, size_t ws_size,
                              hipStream_t stream)
{
    const float* enc = (const float*)d_in[0];
    const int* in_len = (const int*)d_in[1];
    const int* tgt_len = (const int*)d_in[2];
    const float* Wd = (const float*)d_in[3];
    const float* bd = (const float*)d_in[4];
    const float* Wp = (const float*)d_in[5];
    const float* bp = (const float*)d_in[6];
    const float* Wo = (const float*)d_in[7];

    char* ws = (char*)d_ws;
    float* g       = (float*)(ws + 0);             // 128 KB
    float* c_a     = (float*)(ws + 131072);        // 128 KB
    float* c_b     = (float*)(ws + 262144);        // 128 KB
    int* fire_t    = (int*)(ws + 393216);          // 32 KB
    int* n_fired   = (int*)(ws + 425984);          // 64 B
    _Float16* WdT0 = (_Float16*)(ws + 458752);     // 2 MB tiled
    _Float16* WdT1 = (_Float16*)(ws + 2555904);    // 2 MB
    _Float16* Wo0  = (_Float16*)(ws + 4653056);    // 1 MB row-major
    _Float16* Wo1  = (_Float16*)(ws + 5701632);    // 1 MB
    _Float16* C0   = (_Float16*)(ws + 6750208);    // 16 MB
    _Float16* C1   = (_Float16*)(ws + 23527424);   // 16 MB  (end ~40.3 MB)

    float* out0 = (float*)d_out;
    float* out_mask = out0 + (size_t)BSZ * TLEN * OUTDIM;
    float* out_dur = out_mask + (size_t)BSZ * TLEN;
    float* out_qty = out_dur + (size_t)BSZ * TLEN;

    (void)hipMemsetAsync(g, 0, 131072, stream);
    (void)hipMemsetAsync(d_out, 0, (size_t)out_size * 4, stream);

    k0a_split_wd<<<dim3(8, 32), 128, 0, stream>>>(Wd, WdT0, WdT1);
    k0c_split_wo<<<512, 256, 0, stream>>>(Wo, Wo0, Wo1);
    k1_weight_gemm<<<2048, 256, 0, stream>>>(enc, WdT0, WdT1, bd, Wp, g);
    k2_scan<<<BSZ, 256, 0, stream>>>(g, in_len, tgt_len, bp, c_a, c_b,
                                     fire_t, n_fired, out_mask, out_dur, out_qty);
    k3a_compact<<<dim3(MAXF, BSZ), 256, 0, stream>>>(enc, c_a, c_b, fire_t,
                                                     n_fired, C0, C1);
    k3b_outproj<<<dim3(4, 4, BSZ), 256, 0, stream>>>(C0, C1, Wo0, Wo1,
                                                     n_fired, out0);
}

// Round 5
// 590.763 us; speedup vs baseline: 2.1255x; 1.0917x over previous
//
#include <hip/hip_runtime.h>
#include <cstdint>
#include <cstddef>

#define BSZ 16
#define TLEN 2048
#define CDIM 1024
#define OUTDIM 512
#define MAXF 512

typedef _Float16 f16x8 __attribute__((ext_vector_type(8)));
typedef _Float16 f16x4 __attribute__((ext_vector_type(4)));
typedef float f32x16 __attribute__((ext_vector_type(16)));

__device__ __forceinline__ void gl_lds16(const void* g, void* l) {
    __builtin_amdgcn_global_load_lds(
        (const __attribute__((address_space(1))) void*)g,
        (__attribute__((address_space(3))) void*)l, 16, 0, 0);
}

// exact 2-term fp16 split: a = h0 + h1 * 2^-11  (h1 pre-scaled by 2^11)
struct h2pair { _Float16 h0, h1; };
__device__ __forceinline__ h2pair split2(float a) {
    h2pair o;
    o.h0 = (_Float16)a;
    float r = a - (float)o.h0;       // exact (Sterbenz)
    o.h1 = (_Float16)(r * 2048.0f);
    return o;
}

// ============================================================================
// k0a: split Wd into 2 fp16 planes in k1's TILED layout:
// plane[(dut*32+ktl)*4096 + (chunk*128 + n)*8 + j]
// ============================================================================
__global__ __launch_bounds__(128) void k0a_split_wd(
    const float* __restrict__ Wd, _Float16* __restrict__ B0,
    _Float16* __restrict__ B1)
{
    const int dut = blockIdx.x;     // 8
    const int ktl = blockIdx.y;     // 32
    const int r = threadIdx.x;      // 128
    const float* src = Wd + (size_t)(dut * 128 + r) * CDIM + ktl * 32;
    float v[32];
#pragma unroll
    for (int j = 0; j < 8; j++) *(float4*)&v[j * 4] = *(const float4*)(src + j * 4);
    const size_t tb = (size_t)(dut * 32 + ktl) * 4096;
#pragma unroll
    for (int c = 0; c < 4; c++) {
        f16x8 h0, h1;
#pragma unroll
        for (int j = 0; j < 8; j++) {
            h2pair s = split2(v[c * 8 + j]);
            h0[j] = s.h0;
            h1[j] = s.h1;
        }
        *(f16x8*)&B0[tb + (c * 128 + r) * 8] = h0;
        *(f16x8*)&B1[tb + (c * 128 + r) * 8] = h1;
    }
}

// ============================================================================
// k0c: split Wo into 2 fp16 planes, row-major [o][k]
// ============================================================================
__global__ __launch_bounds__(256) void k0c_split_wo(
    const float* __restrict__ Wo, _Float16* __restrict__ W0,
    _Float16* __restrict__ W1)
{
    const int i = (blockIdx.x * 256 + threadIdx.x) * 4;
    float4 v = *(const float4*)(Wo + i);
    f16x4 h0, h1;
    h2pair s0 = split2(v.x); h0[0] = s0.h0; h1[0] = s0.h1;
    h2pair s1 = split2(v.y); h0[1] = s1.h0; h1[1] = s1.h1;
    h2pair s2 = split2(v.z); h0[2] = s2.h0; h1[2] = s2.h1;
    h2pair s3 = split2(v.w); h0[3] = s3.h0; h1[3] = s3.h1;
    *(f16x4*)&W0[i] = h0;
    *(f16x4*)&W1[i] = h1;
}

// ============================================================================
// k1: g[row] = sum_du Wp[du]*relu(enc[row,:].Wd[du,:] + bd[du])
// fp16 2-term split, 3 MFMA products. 128x128x32 tile, double-buffered LDS
// (64 KB): loads for kt+1 issued after the barrier, drained at the NEXT
// barrier (full MFMA window in flight). XCD swizzle: the 8 du-blocks of a
// row-group are consecutive slots on ONE XCD -> A-tile fetched once per XCD.
// ============================================================================
__global__ __launch_bounds__(256, 2) void k1_weight_gemm(
    const float* __restrict__ enc, const _Float16* __restrict__ BT0,
    const _Float16* __restrict__ BT1, const float* __restrict__ bd,
    const float* __restrict__ Wp, float* __restrict__ g)
{
    // 2 buffers x (A0|A1|B0|B1 quarters of 4096 halves) = 32768 halves = 64KB
    __shared__ __align__(16) _Float16 lds[32768];

    const int tid = threadIdx.x;
    const int lane = tid & 63;
    const int wv = tid >> 6;
    const int l5 = lane & 31;
    const int hi = lane >> 5;
    const int mtb = (wv & 1) * 64;
    const int ntb = (wv >> 1) * 64;

    // XCD-aware decode: xcd = bx%8; each xcd handles 32 row-groups x 8 du
    const int bx = blockIdx.x;
    const int xcd = bx & 7;
    const int j = bx >> 3;
    const int rg = xcd * 32 + (j >> 3);
    const int du = j & 7;
    const long row0 = (long)rg * 128;
    const int du0 = du * 128;

    const int sr = tid >> 1;          // A staging row
    const int sh = tid & 1;           // A staging k-half (16 floats)
    const float* aptr = enc + (row0 + sr) * (long)CDIM + sh * 16;

    const _Float16* btile = ((wv >> 1) ? BT1 : BT0) + (size_t)du * 32 * 4096;
    const int bh = wv & 1;            // which half of the B tile this wave DMAs
    const int bofs = 8192 + (wv >> 1) * 4096 + bh * 2048;

    f32x16 acc[2][2], accc[2][2];
#pragma unroll
    for (int mt = 0; mt < 2; mt++)
#pragma unroll
        for (int nt = 0; nt < 2; nt++)
#pragma unroll
            for (int r = 0; r < 16; r++) { acc[mt][nt][r] = 0.f; accc[mt][nt][r] = 0.f; }

    float fa[16];

    // ---- pre-loop: stage tile 0 into buf0, prefetch fa(tile 1) ----
#pragma unroll
    for (int jj = 0; jj < 4; jj++)
        *(float4*)&fa[jj * 4] = *(const float4*)(aptr + jj * 4);
    {
        f16x8 va0[2], va1[2];
#pragma unroll
        for (int c = 0; c < 2; c++)
#pragma unroll
            for (int jj = 0; jj < 8; jj++) {
                h2pair s = split2(fa[c * 8 + jj]);
                va0[c][jj] = s.h0;
                va1[c][jj] = s.h1;
            }
#pragma unroll
        for (int c = 0; c < 2; c++) {
            *(f16x8*)&lds[((sh * 2 + c) * 128 + sr) * 8] = va0[c];
            *(f16x8*)&lds[4096 + ((sh * 2 + c) * 128 + sr) * 8] = va1[c];
        }
#pragma unroll
        for (int c = 0; c < 4; c++)
            gl_lds16(btile + (bh * 256 + c * 64 + lane) * 8,
                     &lds[bofs + c * 512]);
    }
#pragma unroll
    for (int jj = 0; jj < 4; jj++)
        *(float4*)&fa[jj * 4] = *(const float4*)(aptr + 32 + jj * 4);

    for (int kt = 0; kt < 32; ++kt) {
        const int cur = (kt & 1) * 16384;
        const int nxt = ((kt & 1) ^ 1) * 16384;

        __syncthreads();   // buf[cur] complete; buf[nxt] fully consumed

        if (kt < 31) {
            // DMA B(kt+1) into nxt — in flight during this tile's MFMA
#pragma unroll
            for (int c = 0; c < 4; c++)
                gl_lds16(btile + (size_t)(kt + 1) * 4096 + (bh * 256 + c * 64 + lane) * 8,
                         &lds[nxt + bofs + c * 512]);
            // split fa (= tile kt+1) and write A planes into nxt
            f16x8 va0[2], va1[2];
#pragma unroll
            for (int c = 0; c < 2; c++)
#pragma unroll
                for (int jj = 0; jj < 8; jj++) {
                    h2pair s = split2(fa[c * 8 + jj]);
                    va0[c][jj] = s.h0;
                    va1[c][jj] = s.h1;
                }
#pragma unroll
            for (int c = 0; c < 2; c++) {
                *(f16x8*)&lds[nxt + ((sh * 2 + c) * 128 + sr) * 8] = va0[c];
                *(f16x8*)&lds[nxt + 4096 + ((sh * 2 + c) * 128 + sr) * 8] = va1[c];
            }
            if (kt < 30) {
#pragma unroll
                for (int jj = 0; jj < 4; jj++)
                    *(float4*)&fa[jj * 4] = *(const float4*)(aptr + (kt + 2) * 32 + jj * 4);
            }
        }

        // ---- compute on cur ----
#pragma unroll
        for (int ks = 0; ks < 2; ks++) {
            const int ch = ks * 2 + hi;
            f16x8 A0[2], A1[2], B0[2], B1[2];
#pragma unroll
            for (int mt = 0; mt < 2; mt++) {
                const int row = mtb + mt * 32 + l5;
                A0[mt] = *(const f16x8*)&lds[cur + (ch * 128 + row) * 8];
                A1[mt] = *(const f16x8*)&lds[cur + 4096 + (ch * 128 + row) * 8];
            }
#pragma unroll
            for (int nt = 0; nt < 2; nt++) {
                const int row = ntb + nt * 32 + l5;
                B0[nt] = *(const f16x8*)&lds[cur + 8192 + (ch * 128 + row) * 8];
                B1[nt] = *(const f16x8*)&lds[cur + 12288 + (ch * 128 + row) * 8];
            }
#pragma unroll
            for (int mt = 0; mt < 2; mt++)
#pragma unroll
                for (int nt = 0; nt < 2; nt++) {
                    acc[mt][nt] = __builtin_amdgcn_mfma_f32_32x32x16_f16(
                        A0[mt], B0[nt], acc[mt][nt], 0, 0, 0);
                    accc[mt][nt] = __builtin_amdgcn_mfma_f32_32x32x16_f16(
                        A0[mt], B1[nt], accc[mt][nt], 0, 0, 0);
                    accc[mt][nt] = __builtin_amdgcn_mfma_f32_32x32x16_f16(
                        A1[mt], B0[nt], accc[mt][nt], 0, 0, 0);
                }
        }
    }

    // epilogue: h = relu(acc_total + bd[n]); g += Wp[n]*h reduced over n
    float bdv[2], wpv[2];
#pragma unroll
    for (int nt = 0; nt < 2; nt++) {
        int n = du0 + ntb + nt * 32 + l5;
        bdv[nt] = bd[n];
        wpv[nt] = Wp[n];
    }
    float pm[2][16];
#pragma unroll
    for (int mt = 0; mt < 2; mt++)
#pragma unroll
        for (int r = 0; r < 16; r++) {
            float s = 0.f;
#pragma unroll
            for (int nt = 0; nt < 2; nt++) {
                float h = acc[mt][nt][r] + 4.8828125e-4f * accc[mt][nt][r] + bdv[nt];
                h = h > 0.f ? h : 0.f;
                s += wpv[nt] * h;
            }
            s += __shfl_xor(s, 1);
            s += __shfl_xor(s, 2);
            s += __shfl_xor(s, 4);
            s += __shfl_xor(s, 8);
            s += __shfl_xor(s, 16);
            pm[mt][r] = s;
        }
    float out = 0.f;
#pragma unroll
    for (int mt = 0; mt < 2; mt++)
#pragma unroll
        for (int r = 0; r < 16; r++)
            if (l5 == mt * 16 + r) out = pm[mt][r];
    const int mt_sel = l5 >> 4;
    const int r_sel = l5 & 15;
    const int row = mtb + mt_sel * 32 + (r_sel & 3) + 8 * (r_sel >> 2) + 4 * hi;
    atomicAdd(&g[row0 + row], out);
}

// ============================================================================
// k2: per-batch sigmoid + masked sum + scale + sequential scan.
// Scan unrolled x8 with vector LDS loads (batched, independent) so the
// dependent chain runs at VALU latency, not LDS latency. Per-element fp op
// sequence identical to the reference.
// ============================================================================
__global__ __launch_bounds__(256) void k2_scan(
    const float* __restrict__ g, const int* __restrict__ in_len,
    const int* __restrict__ tgt_len, const float* __restrict__ bp,
    float* __restrict__ c_a, float* __restrict__ c_b,
    int* __restrict__ fire_t, int* __restrict__ n_fired,
    float* __restrict__ out_mask, float* __restrict__ out_dur,
    float* __restrict__ out_qty)
{
    __shared__ float w[TLEN];
    __shared__ float ca[TLEN];
    __shared__ float cb[TLEN];
    __shared__ int fires[MAXF];
    __shared__ float ssum[256];
    __shared__ float s_scale;
    __shared__ int s_nf;

    const int b = blockIdx.x;
    const int tid = threadIdx.x;
    const int len = in_len[b];
    const float bpv = bp[0];

    float local = 0.f;
    for (int t = tid; t < TLEN; t += 256) {
        float gv = g[b * TLEN + t] + bpv;
        float s = 1.f / (1.f + expf(-gv));
        float ow = (t < len) ? s : 0.f;
        w[t] = ow;
        local += ow;
    }
    ssum[tid] = local;
    __syncthreads();
    for (int st = 128; st > 0; st >>= 1) {
        if (tid < st) ssum[tid] += ssum[tid + st];
        __syncthreads();
    }
    if (tid == 0) {
        float org_sum = ssum[0];
        out_qty[b] = org_sum;
        s_scale = (float)tgt_len[b] / (org_sum + 1e-8f);
    }
    __syncthreads();
    float scale = s_scale;
    for (int t = tid; t < TLEN; t += 256) w[t] *= scale;
    __syncthreads();

    if (tid == 0) {
        float accw = 0.f;
        int k = 0;
        int t = 0;
        for (; t + 8 <= len; t += 8) {
            float4 wa = *(const float4*)&w[t];
            float4 wb4 = *(const float4*)&w[t + 4];
            float wv8[8] = {wa.x, wa.y, wa.z, wa.w, wb4.x, wb4.y, wb4.z, wb4.w};
#pragma unroll
            for (int u = 0; u < 8; u++) {
                float wt = wv8[u];
                float aw = accw + wt;
                bool f = (aw >= 1.0f);
                float rem = 1.0f - accw;          // exact reference order
                float fb = wt - rem;
                ca[t + u] = f ? rem : wt;
                cb[t + u] = f ? fb : 0.f;
                fires[k & (MAXF - 1)] = t + u;    // commits on fire
                k += f ? 1 : 0;
                accw = f ? fb : aw;
            }
        }
        for (; t < len; t++) {
            float wt = w[t];
            float aw = accw + wt;
            bool f = (aw >= 1.0f);
            float rem = 1.0f - accw;
            float fb = wt - rem;
            ca[t] = f ? rem : wt;
            cb[t] = f ? fb : 0.f;
            fires[k & (MAXF - 1)] = t;
            k += f ? 1 : 0;
            accw = f ? fb : aw;
        }
        s_nf = (k < MAXF) ? k : MAXF;
        n_fired[b] = s_nf;
    }
    __syncthreads();

    for (int t = tid; t < len; t += 256) {
        c_a[b * TLEN + t] = ca[t];
        c_b[b * TLEN + t] = cb[t];
    }
    const int nf = s_nf;
    for (int jj = tid; jj < nf; jj += 256) {
        int tj = fires[jj];
        fire_t[b * MAXF + jj] = tj;
        out_mask[b * TLEN + jj] = 1.0f;
        int prev = (jj == 0) ? 0 : fires[jj - 1];
        out_dur[b * TLEN + jj] = (float)(tj - prev);
    }
    if (tid == 0 && nf == 0) out_mask[b * TLEN] = 1.0f;
}

// ============================================================================
// k3a: compact fired frames (segmented weighted sums, ascending t), writing
// fp16 split planes row-major [b][frame][k]; rows >= n_fired zero-filled.
// ============================================================================
__global__ __launch_bounds__(256) void k3a_compact(
    const float* __restrict__ enc, const float* __restrict__ c_a,
    const float* __restrict__ c_b, const int* __restrict__ fire_t,
    const int* __restrict__ n_fired, _Float16* __restrict__ C0,
    _Float16* __restrict__ C1)
{
    const int b = blockIdx.y;
    const int k = blockIdx.x;
    const int tid = threadIdx.x;
    _Float16* d0 = C0 + ((size_t)b * MAXF + k) * CDIM + tid * 4;
    _Float16* d1 = C1 + ((size_t)b * MAXF + k) * CDIM + tid * 4;
    if (k >= n_fired[b]) {
        f16x4 z = {(_Float16)0.f, (_Float16)0.f, (_Float16)0.f, (_Float16)0.f};
        *(f16x4*)d0 = z;
        *(f16x4*)d1 = z;
        return;
    }
    const int tend = fire_t[b * MAXF + k];
    const int tprev = (k == 0) ? -1 : fire_t[b * MAXF + k - 1];
    float ax = 0.f, ay = 0.f, az = 0.f, aw = 0.f;
    const int tstart = (tprev < 0) ? 0 : tprev;
    for (int t = tstart; t <= tend; t++) {
        float coef = (t == tprev) ? c_b[b * TLEN + t] : c_a[b * TLEN + t];
        const float4 e = *(const float4*)(enc + ((size_t)b * TLEN + t) * CDIM + tid * 4);
        ax += coef * e.x;
        ay += coef * e.y;
        az += coef * e.z;
        aw += coef * e.w;
    }
    f16x4 h0, h1;
    h2pair s0 = split2(ax); h0[0] = s0.h0; h1[0] = s0.h1;
    h2pair s1 = split2(ay); h0[1] = s1.h0; h1[1] = s1.h1;
    h2pair s2 = split2(az); h0[2] = s2.h0; h1[2] = s2.h1;
    h2pair s3 = split2(aw); h0[3] = s3.h0; h1[3] = s3.h1;
    *(f16x4*)d0 = h0;
    *(f16x4*)d1 = h1;
}

// ============================================================================
// k3b: cif_outputs[b,j,o] = compact[b,j,:].Wo[o,:] — fp16-3 MFMA.
// ============================================================================
__global__ __launch_bounds__(256, 2) void k3b_outproj(
    const _Float16* __restrict__ C0, const _Float16* __restrict__ C1,
    const _Float16* __restrict__ W0, const _Float16* __restrict__ W1,
    const int* __restrict__ n_fired, float* __restrict__ out0)
{
    __shared__ __align__(16) _Float16 lds[16384];

    const int b = blockIdx.z;
    const int nf = n_fired[b];
    const int j0 = blockIdx.x * 128;
    if (j0 >= nf) return;
    const int o0 = blockIdx.y * 128;
    const int tid = threadIdx.x;
    const int lane = tid & 63;
    const int wv = tid >> 6;
    const int l5 = lane & 31;
    const int hi = lane >> 5;
    const int mtb = (wv & 1) * 64;
    const int ntb = (wv >> 1) * 64;

    const int sr = tid >> 1;
    const int sh = tid & 1;
    const _Float16* a0p = C0 + ((size_t)b * MAXF + j0 + sr) * CDIM + sh * 16;
    const _Float16* a1p = C1 + ((size_t)b * MAXF + j0 + sr) * CDIM + sh * 16;
    const _Float16* b0p = W0 + (size_t)(o0 + sr) * CDIM + sh * 16;
    const _Float16* b1p = W1 + (size_t)(o0 + sr) * CDIM + sh * 16;

    f32x16 acc[2][2], accc[2][2];
#pragma unroll
    for (int mt = 0; mt < 2; mt++)
#pragma unroll
        for (int nt = 0; nt < 2; nt++)
#pragma unroll
            for (int r = 0; r < 16; r++) { acc[mt][nt][r] = 0.f; accc[mt][nt][r] = 0.f; }

    f16x8 xa0[2], xa1[2], xb0[2], xb1[2];
#pragma unroll
    for (int c = 0; c < 2; c++) {
        xa0[c] = *(const f16x8*)(a0p + c * 8);
        xa1[c] = *(const f16x8*)(a1p + c * 8);
        xb0[c] = *(const f16x8*)(b0p + c * 8);
        xb1[c] = *(const f16x8*)(b1p + c * 8);
    }

    for (int kt = 0; kt < 32; ++kt) {
        __syncthreads();
#pragma unroll
        for (int c = 0; c < 2; c++) {
            *(f16x8*)&lds[((sh * 2 + c) * 128 + sr) * 8] = xa0[c];
            *(f16x8*)&lds[4096 + ((sh * 2 + c) * 128 + sr) * 8] = xa1[c];
            *(f16x8*)&lds[8192 + ((sh * 2 + c) * 128 + sr) * 8] = xb0[c];
            *(f16x8*)&lds[12288 + ((sh * 2 + c) * 128 + sr) * 8] = xb1[c];
        }
        __syncthreads();
        if (kt < 31) {
            const int o = (kt + 1) * 32;
#pragma unroll
            for (int c = 0; c < 2; c++) {
                xa0[c] = *(const f16x8*)(a0p + o + c * 8);
                xa1[c] = *(const f16x8*)(a1p + o + c * 8);
                xb0[c] = *(const f16x8*)(b0p + o + c * 8);
                xb1[c] = *(const f16x8*)(b1p + o + c * 8);
            }
        }
#pragma unroll
        for (int ks = 0; ks < 2; ks++) {
            const int ch = ks * 2 + hi;
            f16x8 A0[2], A1[2], B0[2], B1[2];
#pragma unroll
            for (int mt = 0; mt < 2; mt++) {
                const int row = mtb + mt * 32 + l5;
                A0[mt] = *(const f16x8*)&lds[(ch * 128 + row) * 8];
                A1[mt] = *(const f16x8*)&lds[4096 + (ch * 128 + row) * 8];
            }
#pragma unroll
            for (int nt = 0; nt < 2; nt++) {
                const int row = ntb + nt * 32 + l5;
                B0[nt] = *(const f16x8*)&lds[8192 + (ch * 128 + row) * 8];
                B1[nt] = *(const f16x8*)&lds[12288 + (ch * 128 + row) * 8];
            }
#pragma unroll
            for (int mt = 0; mt < 2; mt++)
#pragma unroll
                for (int nt = 0; nt < 2; nt++) {
                    acc[mt][nt] = __builtin_amdgcn_mfma_f32_32x32x16_f16(
                        A0[mt], B0[nt], acc[mt][nt], 0, 0, 0);
                    accc[mt][nt] = __builtin_amdgcn_mfma_f32_32x32x16_f16(
                        A0[mt], B1[nt], accc[mt][nt], 0, 0, 0);
                    accc[mt][nt] = __builtin_amdgcn_mfma_f32_32x32x16_f16(
                        A1[mt], B0[nt], accc[mt][nt], 0, 0, 0);
                }
        }
    }

#pragma unroll
    for (int mt = 0; mt < 2; mt++)
#pragma unroll
        for (int nt = 0; nt < 2; nt++)
#pragma unroll
            for (int r = 0; r < 16; r++) {
                float val = acc[mt][nt][r] + 4.8828125e-4f * accc[mt][nt][r];
                int m = mtb + mt * 32 + (r & 3) + 8 * (r >> 2) + 4 * hi;
                int col = o0 + ntb + nt * 32 + l5;
                out0[((size_t)b * TLEN + j0 + m) * OUTDIM + col] = val;
            }
}

// ============================================================================
// Host launch
// ============================================================================
extern "C" void kernel_launch(void* const* d_in, const int* in_sizes, int n_in,
                              void* d_out, int out_size, void* d_ws, size_t ws_size,
                              hipStream_t stream)
{
    const float* enc = (const float*)d_in[0];
    const int* in_len = (const int*)d_in[1];
    const int* tgt_len = (const int*)d_in[2];
    const float* Wd = (const float*)d_in[3];
    const float* bd = (const float*)d_in[4];
    const float* Wp = (const float*)d_in[5];
    const float* bp = (const float*)d_in[6];
    const float* Wo = (const float*)d_in[7];

    char* ws = (char*)d_ws;
    float* g       = (float*)(ws + 0);             // 128 KB
    float* c_a     = (float*)(ws + 131072);        // 128 KB
    float* c_b     = (float*)(ws + 262144);        // 128 KB
    int* fire_t    = (int*)(ws + 393216);          // 32 KB
    int* n_fired   = (int*)(ws + 425984);          // 64 B
    _Float16* WdT0 = (_Float16*)(ws + 458752);     // 2 MB tiled
    _Float16* WdT1 = (_Float16*)(ws + 2555904);    // 2 MB
    _Float16* Wo0  = (_Float16*)(ws + 4653056);    // 1 MB row-major
    _Float16* Wo1  = (_Float16*)(ws + 5701632);    // 1 MB
    _Float16* C0   = (_Float16*)(ws + 6750208);    // 16 MB
    _Float16* C1   = (_Float16*)(ws + 23527424);   // 16 MB  (end ~40.3 MB)

    float* out0 = (float*)d_out;
    float* out_mask = out0 + (size_t)BSZ * TLEN * OUTDIM;
    float* out_dur = out_mask + (size_t)BSZ * TLEN;
    float* out_qty = out_dur + (size_t)BSZ * TLEN;

    (void)hipMemsetAsync(g, 0, 131072, stream);
    (void)hipMemsetAsync(d_out, 0, (size_t)out_size * 4, stream);

    k0a_split_wd<<<dim3(8, 32), 128, 0, stream>>>(Wd, WdT0, WdT1);
    k0c_split_wo<<<512, 256, 0, stream>>>(Wo, Wo0, Wo1);
    k1_weight_gemm<<<2048, 256, 0, stream>>>(enc, WdT0, WdT1, bd, Wp, g);
    k2_scan<<<BSZ, 256, 0, stream>>>(g, in_len, tgt_len, bp, c_a, c_b,
                                     fire_t, n_fired, out_mask, out_dur, out_qty);
    k3a_compact<<<dim3(MAXF, BSZ), 256, 0, stream>>>(enc, c_a, c_b, fire_t,
                                                     n_fired, C0, C1);
    k3b_outproj<<<dim3(4, 4, BSZ), 256, 0, stream>>>(C0, C1, Wo0, Wo1,
                                                     n_fired, out0);
}